// Round 6
// baseline (1412.678 us; speedup 1.0000x reference)
//
#include <hip/hip_runtime.h>
#include <hip/hip_bf16.h>

#define DEV __device__ __forceinline__

constexpr int B = 64, D = 256, L = 2048, H = 512, KP = 128;
constexpr float EPS_LN = 1e-6f, EPS_STAT = 1e-10f, EPS_BN = 1e-5f;
constexpr float SCALE = 0.088388347648318447f; // 1/sqrt(128)

typedef __attribute__((ext_vector_type(8))) short short8;
typedef __attribute__((ext_vector_type(4))) short short4_;
typedef __attribute__((ext_vector_type(4))) float float4_;

DEV unsigned short f2bf(float x) {
  unsigned u = __builtin_bit_cast(unsigned, x);
  u += 0x7fffu + ((u >> 16) & 1u);           // RNE
  return (unsigned short)(u >> 16);
}

DEV unsigned pk2bf(float a, float b) {       // two RNE cvts packed into a dword
  return (unsigned)f2bf(a) | ((unsigned)f2bf(b) << 16);
}

DEV float wred(float x) {
  #pragma unroll
  for (int o = 32; o > 0; o >>= 1) x += __shfl_down(x, o, 64);
  return x;
}
DEV float wredmax(float x) {
  #pragma unroll
  for (int o = 32; o > 0; o >>= 1) x = fmaxf(x, __shfl_down(x, o, 64));
  return x;
}

// ---- convert w1/w2 (both layers) to bf16 ----
__global__ void k_convw(const float* __restrict__ w1, const float* __restrict__ w2,
                        unsigned short* __restrict__ w1b, unsigned short* __restrict__ w2b) {
  int n = 2 * H * D;
  for (int i = blockIdx.x * blockDim.x + threadIdx.x; i < n; i += gridDim.x * blockDim.x) {
    w1b[i] = f2bf(w1[i]);
    w2b[i] = f2bf(w2[i]);
  }
}

// ---- P1: fused token-LN stats (m,r) + per-(b,d,tile) partial sums of u,u^2 ----
__global__ __launch_bounds__(512, 4) void k_pass1(
    const float* __restrict__ v, float* __restrict__ m, float* __restrict__ r,
    float* __restrict__ S1p, float* __restrict__ S2p) {
  __shared__ float ut[256 * 65];            // u (fp32), row d stride 65 (pad)
  __shared__ float part1[8][64], part2[8][64];
  __shared__ float mu_s[64], rs_s[64];

  int blk = blockIdx.x;
  int b = blk >> 5, tile = blk & 31, l0 = tile * 64;
  int tid = threadIdx.x, t = tid & 63, dg = tid >> 6;

  const float* vcol = v + ((size_t)b * D + dg * 32) * L + l0 + t;
  float vv[32];
  float s1 = 0.f, s2 = 0.f;
  #pragma unroll
  for (int j = 0; j < 32; ++j) {
    float x = vcol[(size_t)j * L];
    vv[j] = x; s1 += x; s2 += x * x;
  }
  part1[dg][t] = s1; part2[dg][t] = s2;
  __syncthreads();
  if (tid < 64) {
    float a = 0.f, c = 0.f;
    #pragma unroll
    for (int q = 0; q < 8; ++q) { a += part1[q][tid]; c += part2[q][tid]; }
    float mu = a * (1.f / D);
    float var = c * (1.f / D) - mu * mu;
    float rsq = rsqrtf(var + EPS_LN);
    mu_s[tid] = mu; rs_s[tid] = rsq;
    m[b * L + l0 + tid] = mu;
    r[b * L + l0 + tid] = rsq;
  }
  __syncthreads();
  {
    float mu = mu_s[t], rsv = rs_s[t];
    #pragma unroll
    for (int j = 0; j < 32; ++j)
      ut[(dg * 32 + j) * 65 + t] = (vv[j] - mu) * rsv;
  }
  __syncthreads();
  {
    int d = tid >> 1, hf = (tid & 1) * 32;
    float a1 = 0.f, a2 = 0.f;
    #pragma unroll
    for (int l2 = 0; l2 < 32; ++l2) {
      float u = ut[d * 65 + hf + l2];
      a1 += u; a2 += u * u;
    }
    a1 += __shfl_xor(a1, 1, 64);
    a2 += __shfl_xor(a2, 1, 64);
    if ((tid & 1) == 0) {
      S1p[((size_t)b * 32 + tile) * D + d] = a1;
      S2p[((size_t)b * 32 + tile) * D + d] = a2;
    }
  }
}

// ---- per-b: reduce partials -> mu/sd over L -> q -> gw ----
__global__ void k_qproj(const float* __restrict__ S1p, const float* __restrict__ S2p,
                        const float* __restrict__ g, const float* __restrict__ be,
                        const float* __restrict__ wq, const float* __restrict__ wk,
                        float* __restrict__ gw) {
  __shared__ float cat[2 * D];
  __shared__ float qs[KP];
  int b = blockIdx.x, t = threadIdx.x;  // 256 threads
  {
    float s1 = 0.f, s2 = 0.f;
    for (int k = 0; k < 32; ++k) {
      s1 += S1p[((size_t)b * 32 + k) * D + t];
      s2 += S2p[((size_t)b * 32 + k) * D + t];
    }
    s1 *= (1.f / L); s2 *= (1.f / L);
    float gg = g[t];
    cat[t] = gg * s1 + be[t];
    float var = gg * gg * (s2 - s1 * s1);
    cat[D + t] = sqrtf(fmaxf(var, EPS_STAT));
  }
  __syncthreads();
  if (t < KP) {
    float s = 0.f;
    const float* wr = wq + t * 2 * D;
    for (int e = 0; e < 2 * D; ++e) s += cat[e] * wr[e];
    qs[t] = s;
  }
  __syncthreads();
  {
    float s = 0.f;
    for (int k = 0; k < KP; ++k) s += wk[k * D + t] * qs[k];
    gw[b * D + t] = g[t] * SCALE * s;  // beta const dropped (softmax-invariant)
  }
}

// ---- scores[b,l] = r * sum_d (v-m)*gw ----
__global__ void k_scores(const float* __restrict__ v, const float* __restrict__ m,
                         const float* __restrict__ r, const float* __restrict__ gw,
                         float* __restrict__ sc) {
  __shared__ float gws[D];
  int i = blockIdx.x * 256 + threadIdx.x;
  int b = i >> 11, l = i & (L - 1);
  gws[threadIdx.x] = gw[b * D + threadIdx.x];
  __syncthreads();
  const float* p = v + (size_t)b * D * L + l;
  float mm = m[i], rr = r[i], s = 0.f;
  #pragma unroll 8
  for (int d = 0; d < D; ++d) s += (p[(size_t)d * L] - mm) * gws[d];
  sc[i] = s * rr;
}

// ---- softmax (in-block recompute) + weighted stats over L per (b, 32 d-rows) ----
__global__ __launch_bounds__(256) void k_redw(
    const float* __restrict__ v, const float* __restrict__ m, const float* __restrict__ r,
    const float* __restrict__ sc, float* __restrict__ A1, float* __restrict__ A2) {
  __shared__ float ws[L];
  __shared__ float ms[L], rs[L];
  __shared__ float red[4];
  int blk = blockIdx.x;
  int b = blk >> 3, dt = (blk & 7) * 32;
  int tid = threadIdx.x, wv = tid >> 6, lane = tid & 63;

  float xc[8];
  float mx = -1e30f;
  #pragma unroll
  for (int k = 0; k < 8; ++k) {
    float x = sc[b * L + tid + k * 256];
    xc[k] = x; mx = fmaxf(mx, x);
  }
  mx = wredmax(mx);
  if (lane == 0) red[wv] = mx;
  __syncthreads();
  mx = fmaxf(fmaxf(red[0], red[1]), fmaxf(red[2], red[3]));
  float sm = 0.f;
  #pragma unroll
  for (int k = 0; k < 8; ++k) { float e = __expf(xc[k] - mx); xc[k] = e; sm += e; }
  sm = wred(sm);
  __syncthreads();
  if (lane == 0) red[wv] = sm;
  __syncthreads();
  float inv = 1.f / (red[0] + red[1] + red[2] + red[3]);
  #pragma unroll
  for (int k = 0; k < 8; ++k) ws[tid + k * 256] = xc[k] * inv;
  for (int l = tid; l < L; l += 256) { ms[l] = m[b * L + l]; rs[l] = r[b * L + l]; }
  __syncthreads();

  for (int j = 0; j < 8; ++j) {
    int d = dt + wv * 8 + j;
    const float* row = v + ((size_t)b * D + d) * L;
    float a1 = 0.f, a2 = 0.f;
    #pragma unroll
    for (int k2 = 0; k2 < 8; ++k2) {
      int l = lane * 4 + k2 * 256;
      float4_ x4 = *(const float4_*)&row[l];
      #pragma unroll
      for (int i = 0; i < 4; ++i) {
        float u = (x4[i] - ms[l + i]) * rs[l + i];
        float w = ws[l + i];
        a1 += w * u; a2 += w * u * u;
      }
    }
    a1 = wred(a1); a2 = wred(a2);
    if (lane == 0) { A1[b * D + d] = a1; A2[b * D + d] = a2; }
  }
}

// ---- per-b: att_mean/std -> skip (this layer) + fcq ----
__global__ void k_skip(const float* __restrict__ A1, const float* __restrict__ A2,
                       const float* __restrict__ g, const float* __restrict__ be,
                       const float* __restrict__ fcw, const float* __restrict__ fcb,
                       const float* __restrict__ fcqw,
                       float* __restrict__ skip_i, float* __restrict__ fcq) {
  __shared__ float am[D], as_[D];
  int b = blockIdx.x, t = threadIdx.x;
  {
    float a1 = A1[b * D + t], a2 = A2[b * D + t], gg = g[t];
    am[t] = gg * a1 + be[t];
    float var = gg * gg * (a2 - a1 * a1);
    as_[t] = sqrtf(fmaxf(var, EPS_STAT));
  }
  __syncthreads();
  float s = fcb[t], fq = 0.f;
  const float* wr = fcw + t * 2 * D;
  const float* qr = fcqw + t * D;
  for (int d = 0; d < D; ++d) {
    s += wr[d] * am[d] + wr[D + d] * as_[d];
    fq += qr[d] * am[d];
  }
  skip_i[b * D + t] = s;
  fcq[b * D + t] = fq;
}

// ---- fused FFN: streaming multi-tile blocks with register double-buffered v ----
// 512 blocks (2/CU, one scheduling round). Block = (b, group of 4 tiles x 64 tok).
// us[] 64KB: a_tile groups 0..31; h1 group ((h>>3)+32)&63 (h<256 upper, h>=256 alias).
constexpr int MT = 64;
constexpr int NTILE = 4;

#define GEMM1_HALF(H0, ACC)                                                          \
  {                                                                                  \
    const unsigned short* wp0 = w1b + (size_t)((H0) + lr) * D + lq * 8;              \
    const unsigned short* wp1 = wp0 + 16 * D;                                        \
    int abase = lq * 512 + lr * 8;                                                   \
    short8 af0 = *(const short8*)wp0;                                                \
    short8 af1 = *(const short8*)wp1;                                                \
    short8 bf0 = *(const short8*)&us[abase];                                         \
    short8 bf1 = *(const short8*)&us[abase + 128];                                   \
    short8 bf2 = *(const short8*)&us[abase + 256];                                   \
    short8 bf3 = *(const short8*)&us[abase + 384];                                   \
    _Pragma("unroll")                                                                \
    for (int kk = 0; kk < 8; ++kk) {                                                 \
      short8 an0, an1, bn0, bn1, bn2, bn3;                                           \
      if (kk < 7) {                                                                  \
        an0 = *(const short8*)(wp0 + (kk + 1) * 32);                                 \
        an1 = *(const short8*)(wp1 + (kk + 1) * 32);                                 \
        int nb = abase + (kk + 1) * 2048;                                            \
        bn0 = *(const short8*)&us[nb];                                               \
        bn1 = *(const short8*)&us[nb + 128];                                         \
        bn2 = *(const short8*)&us[nb + 256];                                         \
        bn3 = *(const short8*)&us[nb + 384];                                         \
      }                                                                              \
      ACC[0][0] = __builtin_amdgcn_mfma_f32_16x16x32_bf16(af0, bf0, ACC[0][0],0,0,0);\
      ACC[0][1] = __builtin_amdgcn_mfma_f32_16x16x32_bf16(af0, bf1, ACC[0][1],0,0,0);\
      ACC[0][2] = __builtin_amdgcn_mfma_f32_16x16x32_bf16(af0, bf2, ACC[0][2],0,0,0);\
      ACC[0][3] = __builtin_amdgcn_mfma_f32_16x16x32_bf16(af0, bf3, ACC[0][3],0,0,0);\
      ACC[1][0] = __builtin_amdgcn_mfma_f32_16x16x32_bf16(af1, bf0, ACC[1][0],0,0,0);\
      ACC[1][1] = __builtin_amdgcn_mfma_f32_16x16x32_bf16(af1, bf1, ACC[1][1],0,0,0);\
      ACC[1][2] = __builtin_amdgcn_mfma_f32_16x16x32_bf16(af1, bf2, ACC[1][2],0,0,0);\
      ACC[1][3] = __builtin_amdgcn_mfma_f32_16x16x32_bf16(af1, bf3, ACC[1][3],0,0,0);\
      af0 = an0; af1 = an1; bf0 = bn0; bf1 = bn1; bf2 = bn2; bf3 = bn3;              \
    }                                                                                \
  }

#define H1_WRITE(H0, ACC)                                                            \
  {                                                                                  \
    _Pragma("unroll")                                                                \
    for (int mh = 0; mh < 2; ++mh) {                                                 \
      int hb = (H0) + mh * 16 + lq * 4;                                              \
      float b10 = b1[hb], b11 = b1[hb + 1], b12 = b1[hb + 2], b13 = b1[hb + 3];      \
      int grp = ((hb >> 3) + 32) & 63;                                               \
      int jh0 = hb & 7;                                                              \
      _Pragma("unroll")                                                              \
      for (int nt = 0; nt < 4; ++nt) {                                               \
        int tok = nt * 16 + lr;                                                      \
        uint2 pk;                                                                    \
        pk.x = pk2bf(fmaxf(ACC[mh][nt][0] + b10, 0.f),                               \
                     fmaxf(ACC[mh][nt][1] + b11, 0.f));                              \
        pk.y = pk2bf(fmaxf(ACC[mh][nt][2] + b12, 0.f),                               \
                     fmaxf(ACC[mh][nt][3] + b13, 0.f));                              \
        *(uint2*)&us[grp * 512 + tok * 8 + jh0] = pk;                                \
      }                                                                              \
    }                                                                                \
  }

#define GEMM2_HALF(M0, ACC2)                                                         \
  {                                                                                  \
    const unsigned short* wp = w2b + (size_t)((M0) + lr) * H + lq * 8;               \
    int hb0 = ((lq + 32) & 63) * 512 + lr * 8;                                       \
    short8 wf = *(const short8*)wp;                                                  \
    short8 hf0 = *(const short8*)&us[hb0];                                           \
    short8 hf1 = *(const short8*)&us[hb0 + 128];                                     \
    short8 hf2 = *(const short8*)&us[hb0 + 256];                                     \
    short8 hf3 = *(const short8*)&us[hb0 + 384];                                     \
    _Pragma("unroll")                                                                \
    for (int kk = 0; kk < 16; ++kk) {                                                \
      short8 wn, hn0, hn1, hn2, hn3;                                                 \
      if (kk < 15) {                                                                 \
        wn = *(const short8*)(wp + (kk + 1) * 32);                                   \
        int hb = (((kk + 1) * 4 + lq + 32) & 63) * 512 + lr * 8;                     \
        hn0 = *(const short8*)&us[hb];                                               \
        hn1 = *(const short8*)&us[hb + 128];                                         \
        hn2 = *(const short8*)&us[hb + 256];                                         \
        hn3 = *(const short8*)&us[hb + 384];                                         \
      }                                                                              \
      ACC2[0] = __builtin_amdgcn_mfma_f32_16x16x32_bf16(wf, hf0, ACC2[0], 0, 0, 0);  \
      ACC2[1] = __builtin_amdgcn_mfma_f32_16x16x32_bf16(wf, hf1, ACC2[1], 0, 0, 0);  \
      ACC2[2] = __builtin_amdgcn_mfma_f32_16x16x32_bf16(wf, hf2, ACC2[2], 0, 0, 0);  \
      ACC2[3] = __builtin_amdgcn_mfma_f32_16x16x32_bf16(wf, hf3, ACC2[3], 0, 0, 0);  \
      wf = wn; hf0 = hn0; hf1 = hn1; hf2 = hn2; hf3 = hn3;                           \
    }                                                                                \
  }

#define EPI_HALF(M0, ACC2)                                                           \
  {                                                                                  \
    _Pragma("unroll")                                                                \
    for (int i = 0; i < 4; ++i) {                                                    \
      int d = (M0) + lq * 4 + i;                                                     \
      float bb = b2_s[d] + fcq_s[d];                                                 \
      size_t rowoff = ((size_t)b * D + d) * L + l0;                                  \
      _Pragma("unroll")                                                              \
      for (int nt = 0; nt < 4; ++nt) {                                               \
        int tok = nt * 16 + lr;                                                      \
        dst[rowoff + tok] = ACC2[nt][i] + bb + src[rowoff + tok];                    \
      }                                                                              \
    }                                                                                \
  }

__global__ __launch_bounds__(512, 4) void k_ffn(
    const float* src, float* dst, const float* __restrict__ fcq,
    const unsigned short* __restrict__ w1b, const float* __restrict__ b1,
    const unsigned short* __restrict__ w2b, const float* __restrict__ b2,
    const float* __restrict__ g, const float* __restrict__ be) {
  __shared__ __align__(16) unsigned short us[32768];   // 64 KB
  __shared__ float fcq_s[D], g_s[D], be_s[D], b2_s[D];
  __shared__ float part1[8][MT], part2[8][MT];
  __shared__ float mu_s[MT], rs_s[MT];

  int blk = blockIdx.x;          // 512 blocks
  int b = blk >> 3;
  int tg = blk & 7;              // owns tokens [tg*256, tg*256+256)
  int tid = threadIdx.x;
  int t = tid & 63, dg = tid >> 6;
  int wv = tid >> 6, lane = tid & 63, lr = lane & 15, lq = lane >> 4;

  if (tid < D) {
    fcq_s[tid] = fcq[b * D + tid];
    g_s[tid] = g[tid]; be_s[tid] = be[tid]; b2_s[tid] = b2[tid];
  }
  __syncthreads();

  const float* vbase = src + ((size_t)b * D + dg * 32) * L + tg * (NTILE * 64) + t;
  float vv[32], vv2[32];
  #pragma unroll
  for (int j = 0; j < 32; ++j) vv[j] = vbase[(size_t)j * L];

  for (int it = 0; it < NTILE; ++it) {
    int l0 = tg * (NTILE * 64) + it * 64;

    // ---- stage 1: add fcq, token LN stats (vv loaded last iter / prologue) ----
    float s1 = 0.f, s2 = 0.f;
    #pragma unroll
    for (int j = 0; j < 32; ++j) {
      float x = vv[j] + fcq_s[dg * 32 + j];
      vv[j] = x; s1 += x; s2 += x * x;
    }
    part1[dg][t] = s1; part2[dg][t] = s2;
    __syncthreads();
    if (tid < MT) {
      float a = 0.f, c = 0.f;
      #pragma unroll
      for (int q = 0; q < 8; ++q) { a += part1[q][tid]; c += part2[q][tid]; }
      float mu = a * (1.f / D);
      float var = c * (1.f / D) - mu * mu;
      mu_s[tid] = mu; rs_s[tid] = rsqrtf(var + EPS_LN);
    }
    __syncthreads();
    {
      float mu = mu_s[t], rs = rs_s[t];
      #pragma unroll
      for (int lq2 = 0; lq2 < 4; ++lq2) {
        uint4 pw;
        unsigned* pp = &pw.x;
        #pragma unroll
        for (int jj = 0; jj < 4; ++jj) {
          int d0 = dg * 32 + lq2 * 8 + jj * 2;
          pp[jj] = pk2bf((vv[lq2 * 8 + jj * 2]     - mu) * rs * g_s[d0]     + be_s[d0],
                         (vv[lq2 * 8 + jj * 2 + 1] - mu) * rs * g_s[d0 + 1] + be_s[d0 + 1]);
        }
        *(uint4*)&us[((dg * 4 + lq2) * 64 + t) * 8] = pw;
      }
    }
    // ---- prefetch next tile's v into registers (rides under GEMM1+GEMM2) ----
    if (it < NTILE - 1) {
      #pragma unroll
      for (int j = 0; j < 32; ++j) vv2[j] = vbase[(it + 1) * 64 + (size_t)j * L];
    }
    __syncthreads();

    float4_ zero = {0.f, 0.f, 0.f, 0.f};

    // ---- GEMM1 phase A: h in [wv*32, +32) -> h1 upper ----
    {
      float4_ accA[2][4];
      #pragma unroll
      for (int i = 0; i < 2; ++i)
        #pragma unroll
        for (int j = 0; j < 4; ++j) accA[i][j] = zero;
      GEMM1_HALF(wv * 32, accA)
      H1_WRITE(wv * 32, accA)
    }
    // ---- GEMM1 phase B: h in [256+wv*32, +32) -> h1 lower (alias a_tile) ----
    {
      float4_ accB[2][4];
      #pragma unroll
      for (int i = 0; i < 2; ++i)
        #pragma unroll
        for (int j = 0; j < 4; ++j) accB[i][j] = zero;
      GEMM1_HALF(256 + wv * 32, accB)
      __syncthreads();               // all a_tile reads done (WAR)
      H1_WRITE(256 + wv * 32, accB)
    }
    __syncthreads();                 // h1 fully visible

    // ---- GEMM2 phases ----
    {
      float4_ acc2[4];
      #pragma unroll
      for (int j = 0; j < 4; ++j) acc2[j] = zero;
      GEMM2_HALF(wv * 16, acc2)
      EPI_HALF(wv * 16, acc2)
    }
    {
      float4_ acc2[4];
      #pragma unroll
      for (int j = 0; j < 4; ++j) acc2[j] = zero;
      GEMM2_HALF(128 + wv * 16, acc2)
      EPI_HALF(128 + wv * 16, acc2)
    }
    __syncthreads();                 // us free for next tile's pack
    if (it < NTILE - 1) {
      #pragma unroll
      for (int j = 0; j < 32; ++j) vv[j] = vv2[j];
    }
  }
}

// ---- final: y = relu(skip0+skip1); batchnorm over B per channel d ----
__global__ void k_bn(const float* __restrict__ s0, const float* __restrict__ s1,
                     float* __restrict__ out) {
  int d = threadIdx.x;
  float s = 0.f, q = 0.f;
  for (int b = 0; b < B; ++b) {
    float y = fmaxf(s0[b * D + d] + s1[b * D + d], 0.f);
    s += y; q += y * y;
  }
  float mu = s * (1.f / B);
  float var = q * (1.f / B) - mu * mu;
  float rs = rsqrtf(var + EPS_BN);
  for (int b = 0; b < B; ++b) {
    float y = fmaxf(s0[b * D + d] + s1[b * D + d], 0.f);
    out[b * D + d] = (y - mu) * rs;
  }
}

extern "C" void kernel_launch(void* const* d_in, const int* in_sizes, int n_in,
                              void* d_out, int out_size, void* d_ws, size_t ws_size,
                              hipStream_t stream) {
  const float* x    = (const float*)d_in[0];
  const float* wk   = (const float*)d_in[1];
  const float* wq   = (const float*)d_in[2];
  const float* fcqw = (const float*)d_in[3];
  const float* fcw  = (const float*)d_in[4];
  const float* fcb  = (const float*)d_in[5];
  const float* ag   = (const float*)d_in[6];
  const float* abt  = (const float*)d_in[7];
  const float* w1   = (const float*)d_in[8];
  const float* b1   = (const float*)d_in[9];
  const float* w2   = (const float*)d_in[10];
  const float* b2   = (const float*)d_in[11];
  const float* fg   = (const float*)d_in[12];
  const float* fb   = (const float*)d_in[13];
  float* out = (float*)d_out;

  char* p = (char*)d_ws;
  float* v_ws = (float*)p;  p += (size_t)B * D * L * 4;
  float* m    = (float*)p;  p += (size_t)B * L * 4;
  float* r    = (float*)p;  p += (size_t)B * L * 4;
  float* sc   = (float*)p;  p += (size_t)B * L * 4;
  float* S1p  = (float*)p;  p += (size_t)B * 32 * D * 4;
  float* S2p  = (float*)p;  p += (size_t)B * 32 * D * 4;
  float* gw   = (float*)p;  p += (size_t)B * D * 4;
  float* A1   = (float*)p;  p += (size_t)B * D * 4;
  float* A2   = (float*)p;  p += (size_t)B * D * 4;
  float* fcqv = (float*)p;  p += (size_t)B * D * 4;
  float* sk0  = (float*)p;  p += (size_t)B * D * 4;
  float* sk1  = (float*)p;  p += (size_t)B * D * 4;
  unsigned short* w1b = (unsigned short*)p; p += (size_t)2 * H * D * 2;
  unsigned short* w2b = (unsigned short*)p; p += (size_t)2 * D * H * 2;

  k_convw<<<512, 256, 0, stream>>>(w1, w2, w1b, w2b);

  for (int i = 0; i < 2; ++i) {
    const float* src = (i == 0) ? x : v_ws;
    float* dst = v_ws;
    k_pass1<<<B * 32, 512, 0, stream>>>(src, m, r, S1p, S2p);
    k_qproj<<<B, 256, 0, stream>>>(S1p, S2p, ag + i * D, abt + i * D,
                                   wq + (size_t)i * KP * 2 * D,
                                   wk + (size_t)i * KP * D, gw);
    k_scores<<<B * L / 256, 256, 0, stream>>>(src, m, r, gw, sc);
    k_redw<<<B * 8, 256, 0, stream>>>(src, m, r, sc, A1, A2);
    k_skip<<<B, 256, 0, stream>>>(A1, A2, ag + i * D, abt + i * D,
                                  fcw + (size_t)i * D * 2 * D, fcb + i * D,
                                  fcqw + (size_t)i * D * D,
                                  (i == 0) ? sk0 : sk1, fcqv);
    k_ffn<<<B * 8, 512, 0, stream>>>(src, dst, fcqv,
                                     w1b + (size_t)i * H * D, b1 + i * H,
                                     w2b + (size_t)i * D * H, b2 + i * D,
                                     fg + i * D, fb + i * D);
  }
  k_bn<<<1, 256, 0, stream>>>(sk0, sk1, out);
}

// Round 7
// 812.566 us; speedup vs baseline: 1.7385x; 1.7385x over previous
//
#include <hip/hip_runtime.h>
#include <hip/hip_bf16.h>

#define DEV __device__ __forceinline__

constexpr int B = 64, D = 256, L = 2048, H = 512, KP = 128;
constexpr float EPS_LN = 1e-6f, EPS_STAT = 1e-10f, EPS_BN = 1e-5f;
constexpr float SCALE = 0.088388347648318447f; // 1/sqrt(128)

typedef __attribute__((ext_vector_type(8))) short short8;
typedef __attribute__((ext_vector_type(4))) short short4_;
typedef __attribute__((ext_vector_type(4))) float float4_;

DEV unsigned short f2bf(float x) {
  unsigned u = __builtin_bit_cast(unsigned, x);
  u += 0x7fffu + ((u >> 16) & 1u);           // RNE
  return (unsigned short)(u >> 16);
}

DEV unsigned pk2bf(float a, float b) {       // two RNE cvts packed into a dword
  return (unsigned)f2bf(a) | ((unsigned)f2bf(b) << 16);
}

DEV float wred(float x) {
  #pragma unroll
  for (int o = 32; o > 0; o >>= 1) x += __shfl_down(x, o, 64);
  return x;
}
DEV float wredmax(float x) {
  #pragma unroll
  for (int o = 32; o > 0; o >>= 1) x = fmaxf(x, __shfl_down(x, o, 64));
  return x;
}

// ---- convert w1/w2 (both layers) to bf16 ----
__global__ void k_convw(const float* __restrict__ w1, const float* __restrict__ w2,
                        unsigned short* __restrict__ w1b, unsigned short* __restrict__ w2b) {
  int n = 2 * H * D;
  for (int i = blockIdx.x * blockDim.x + threadIdx.x; i < n; i += gridDim.x * blockDim.x) {
    w1b[i] = f2bf(w1[i]);
    w2b[i] = f2bf(w2[i]);
  }
}

// ---- P1: fused token-LN stats (m,r) + per-(b,d,tile) partial sums of u,u^2 ----
__global__ __launch_bounds__(512, 4) void k_pass1(
    const float* __restrict__ v, float* __restrict__ m, float* __restrict__ r,
    float* __restrict__ S1p, float* __restrict__ S2p) {
  __shared__ float ut[256 * 65];            // u (fp32), row d stride 65 (pad)
  __shared__ float part1[8][64], part2[8][64];
  __shared__ float mu_s[64], rs_s[64];

  int blk = blockIdx.x;
  int b = blk >> 5, tile = blk & 31, l0 = tile * 64;
  int tid = threadIdx.x, t = tid & 63, dg = tid >> 6;

  const float* vcol = v + ((size_t)b * D + dg * 32) * L + l0 + t;
  float vv[32];
  float s1 = 0.f, s2 = 0.f;
  #pragma unroll
  for (int j = 0; j < 32; ++j) {
    float x = vcol[(size_t)j * L];
    vv[j] = x; s1 += x; s2 += x * x;
  }
  part1[dg][t] = s1; part2[dg][t] = s2;
  __syncthreads();
  if (tid < 64) {
    float a = 0.f, c = 0.f;
    #pragma unroll
    for (int q = 0; q < 8; ++q) { a += part1[q][tid]; c += part2[q][tid]; }
    float mu = a * (1.f / D);
    float var = c * (1.f / D) - mu * mu;
    float rsq = rsqrtf(var + EPS_LN);
    mu_s[tid] = mu; rs_s[tid] = rsq;
    m[b * L + l0 + tid] = mu;
    r[b * L + l0 + tid] = rsq;
  }
  __syncthreads();
  {
    float mu = mu_s[t], rsv = rs_s[t];
    #pragma unroll
    for (int j = 0; j < 32; ++j)
      ut[(dg * 32 + j) * 65 + t] = (vv[j] - mu) * rsv;
  }
  __syncthreads();
  {
    int d = tid >> 1, hf = (tid & 1) * 32;
    float a1 = 0.f, a2 = 0.f;
    #pragma unroll
    for (int l2 = 0; l2 < 32; ++l2) {
      float u = ut[d * 65 + hf + l2];
      a1 += u; a2 += u * u;
    }
    a1 += __shfl_xor(a1, 1, 64);
    a2 += __shfl_xor(a2, 1, 64);
    if ((tid & 1) == 0) {
      S1p[((size_t)b * 32 + tile) * D + d] = a1;
      S2p[((size_t)b * 32 + tile) * D + d] = a2;
    }
  }
}

// ---- per-b: reduce partials -> mu/sd over L -> q -> gw ----
__global__ void k_qproj(const float* __restrict__ S1p, const float* __restrict__ S2p,
                        const float* __restrict__ g, const float* __restrict__ be,
                        const float* __restrict__ wq, const float* __restrict__ wk,
                        float* __restrict__ gw) {
  __shared__ float cat[2 * D];
  __shared__ float qs[KP];
  int b = blockIdx.x, t = threadIdx.x;  // 256 threads
  {
    float s1 = 0.f, s2 = 0.f;
    for (int k = 0; k < 32; ++k) {
      s1 += S1p[((size_t)b * 32 + k) * D + t];
      s2 += S2p[((size_t)b * 32 + k) * D + t];
    }
    s1 *= (1.f / L); s2 *= (1.f / L);
    float gg = g[t];
    cat[t] = gg * s1 + be[t];
    float var = gg * gg * (s2 - s1 * s1);
    cat[D + t] = sqrtf(fmaxf(var, EPS_STAT));
  }
  __syncthreads();
  if (t < KP) {
    float s = 0.f;
    const float* wr = wq + t * 2 * D;
    for (int e = 0; e < 2 * D; ++e) s += cat[e] * wr[e];
    qs[t] = s;
  }
  __syncthreads();
  {
    float s = 0.f;
    for (int k = 0; k < KP; ++k) s += wk[k * D + t] * qs[k];
    gw[b * D + t] = g[t] * SCALE * s;  // beta const dropped (softmax-invariant)
  }
}

// ---- scores[b,l] = r * sum_d (v-m)*gw ----
__global__ void k_scores(const float* __restrict__ v, const float* __restrict__ m,
                         const float* __restrict__ r, const float* __restrict__ gw,
                         float* __restrict__ sc) {
  __shared__ float gws[D];
  int i = blockIdx.x * 256 + threadIdx.x;
  int b = i >> 11, l = i & (L - 1);
  gws[threadIdx.x] = gw[b * D + threadIdx.x];
  __syncthreads();
  const float* p = v + (size_t)b * D * L + l;
  float mm = m[i], rr = r[i], s = 0.f;
  #pragma unroll 8
  for (int d = 0; d < D; ++d) s += (p[(size_t)d * L] - mm) * gws[d];
  sc[i] = s * rr;
}

// ---- softmax (in-block recompute) + weighted stats over L per (b, 32 d-rows) ----
__global__ __launch_bounds__(256) void k_redw(
    const float* __restrict__ v, const float* __restrict__ m, const float* __restrict__ r,
    const float* __restrict__ sc, float* __restrict__ A1, float* __restrict__ A2) {
  __shared__ float ws[L];
  __shared__ float ms[L], rs[L];
  __shared__ float red[4];
  int blk = blockIdx.x;
  int b = blk >> 3, dt = (blk & 7) * 32;
  int tid = threadIdx.x, wv = tid >> 6, lane = tid & 63;

  float xc[8];
  float mx = -1e30f;
  #pragma unroll
  for (int k = 0; k < 8; ++k) {
    float x = sc[b * L + tid + k * 256];
    xc[k] = x; mx = fmaxf(mx, x);
  }
  mx = wredmax(mx);
  if (lane == 0) red[wv] = mx;
  __syncthreads();
  mx = fmaxf(fmaxf(red[0], red[1]), fmaxf(red[2], red[3]));
  float sm = 0.f;
  #pragma unroll
  for (int k = 0; k < 8; ++k) { float e = __expf(xc[k] - mx); xc[k] = e; sm += e; }
  sm = wred(sm);
  __syncthreads();
  if (lane == 0) red[wv] = sm;
  __syncthreads();
  float inv = 1.f / (red[0] + red[1] + red[2] + red[3]);
  #pragma unroll
  for (int k = 0; k < 8; ++k) ws[tid + k * 256] = xc[k] * inv;
  for (int l = tid; l < L; l += 256) { ms[l] = m[b * L + l]; rs[l] = r[b * L + l]; }
  __syncthreads();

  for (int j = 0; j < 8; ++j) {
    int d = dt + wv * 8 + j;
    const float* row = v + ((size_t)b * D + d) * L;
    float a1 = 0.f, a2 = 0.f;
    #pragma unroll
    for (int k2 = 0; k2 < 8; ++k2) {
      int l = lane * 4 + k2 * 256;
      float4_ x4 = *(const float4_*)&row[l];
      #pragma unroll
      for (int i = 0; i < 4; ++i) {
        float u = (x4[i] - ms[l + i]) * rs[l + i];
        float w = ws[l + i];
        a1 += w * u; a2 += w * u * u;
      }
    }
    a1 = wred(a1); a2 = wred(a2);
    if (lane == 0) { A1[b * D + d] = a1; A2[b * D + d] = a2; }
  }
}

// ---- per-b: att_mean/std -> skip (this layer) + fcq ----
__global__ void k_skip(const float* __restrict__ A1, const float* __restrict__ A2,
                       const float* __restrict__ g, const float* __restrict__ be,
                       const float* __restrict__ fcw, const float* __restrict__ fcb,
                       const float* __restrict__ fcqw,
                       float* __restrict__ skip_i, float* __restrict__ fcq) {
  __shared__ float am[D], as_[D];
  int b = blockIdx.x, t = threadIdx.x;
  {
    float a1 = A1[b * D + t], a2 = A2[b * D + t], gg = g[t];
    am[t] = gg * a1 + be[t];
    float var = gg * gg * (a2 - a1 * a1);
    as_[t] = sqrtf(fmaxf(var, EPS_STAT));
  }
  __syncthreads();
  float s = fcb[t], fq = 0.f;
  const float* wr = fcw + t * 2 * D;
  const float* qr = fcqw + t * D;
  for (int d = 0; d < D; ++d) {
    s += wr[d] * am[d] + wr[D + d] * as_[d];
    fq += qr[d] * am[d];
  }
  skip_i[b * D + t] = s;
  fcq[b * D + t] = fq;
}

// ---- fused FFN: round-4 structure (2048 single-tile blocks, L2-friendly) ----
// + wide register prefetch of ALL weight fragments per half-GEMM (depth-8/16
//   instead of depth-1: one L2 latency per half-GEMM, not per kk).
// us[] 64KB: a_tile groups 0..31; h1 group ((h>>3)+32)&63 (h<256 upper, h>=256 alias).
constexpr int MT = 64;

#define GEMM1_HALF(H0, ACC)                                                          \
  {                                                                                  \
    const unsigned short* wp0 = w1b + (size_t)((H0) + lr) * D + lq * 8;              \
    const unsigned short* wp1 = wp0 + 16 * D;                                        \
    short8 wr0[8], wr1[8];                                                           \
    _Pragma("unroll")                                                                \
    for (int kk = 0; kk < 8; ++kk) {                                                 \
      wr0[kk] = *(const short8*)(wp0 + kk * 32);                                     \
      wr1[kk] = *(const short8*)(wp1 + kk * 32);                                     \
    }                                                                                \
    int abase = lq * 512 + lr * 8;                                                   \
    _Pragma("unroll")                                                                \
    for (int kk = 0; kk < 8; ++kk) {                                                 \
      int nb = abase + kk * 2048;                                                    \
      short8 bf0 = *(const short8*)&us[nb];                                          \
      short8 bf1 = *(const short8*)&us[nb + 128];                                    \
      short8 bf2 = *(const short8*)&us[nb + 256];                                    \
      short8 bf3 = *(const short8*)&us[nb + 384];                                    \
      ACC[0][0] = __builtin_amdgcn_mfma_f32_16x16x32_bf16(wr0[kk], bf0, ACC[0][0],0,0,0);\
      ACC[0][1] = __builtin_amdgcn_mfma_f32_16x16x32_bf16(wr0[kk], bf1, ACC[0][1],0,0,0);\
      ACC[0][2] = __builtin_amdgcn_mfma_f32_16x16x32_bf16(wr0[kk], bf2, ACC[0][2],0,0,0);\
      ACC[0][3] = __builtin_amdgcn_mfma_f32_16x16x32_bf16(wr0[kk], bf3, ACC[0][3],0,0,0);\
      ACC[1][0] = __builtin_amdgcn_mfma_f32_16x16x32_bf16(wr1[kk], bf0, ACC[1][0],0,0,0);\
      ACC[1][1] = __builtin_amdgcn_mfma_f32_16x16x32_bf16(wr1[kk], bf1, ACC[1][1],0,0,0);\
      ACC[1][2] = __builtin_amdgcn_mfma_f32_16x16x32_bf16(wr1[kk], bf2, ACC[1][2],0,0,0);\
      ACC[1][3] = __builtin_amdgcn_mfma_f32_16x16x32_bf16(wr1[kk], bf3, ACC[1][3],0,0,0);\
    }                                                                                \
  }

#define H1_WRITE(H0, ACC)                                                            \
  {                                                                                  \
    _Pragma("unroll")                                                                \
    for (int mh = 0; mh < 2; ++mh) {                                                 \
      int hb = (H0) + mh * 16 + lq * 4;                                              \
      float b10 = b1[hb], b11 = b1[hb + 1], b12 = b1[hb + 2], b13 = b1[hb + 3];      \
      int grp = ((hb >> 3) + 32) & 63;                                               \
      int jh0 = hb & 7;                                                              \
      _Pragma("unroll")                                                              \
      for (int nt = 0; nt < 4; ++nt) {                                               \
        int tok = nt * 16 + lr;                                                      \
        uint2 pk;                                                                    \
        pk.x = pk2bf(fmaxf(ACC[mh][nt][0] + b10, 0.f),                               \
                     fmaxf(ACC[mh][nt][1] + b11, 0.f));                              \
        pk.y = pk2bf(fmaxf(ACC[mh][nt][2] + b12, 0.f),                               \
                     fmaxf(ACC[mh][nt][3] + b13, 0.f));                              \
        *(uint2*)&us[grp * 512 + tok * 8 + jh0] = pk;                                \
      }                                                                              \
    }                                                                                \
  }

#define GEMM2_HALF(M0, ACC2)                                                         \
  {                                                                                  \
    const unsigned short* wp = w2b + (size_t)((M0) + lr) * H + lq * 8;               \
    short8 wrg[16];                                                                  \
    _Pragma("unroll")                                                                \
    for (int kk = 0; kk < 16; ++kk) wrg[kk] = *(const short8*)(wp + kk * 32);        \
    _Pragma("unroll")                                                                \
    for (int kk = 0; kk < 16; ++kk) {                                                \
      int hb = ((kk * 4 + lq + 32) & 63) * 512 + lr * 8;                             \
      short8 hf0 = *(const short8*)&us[hb];                                          \
      short8 hf1 = *(const short8*)&us[hb + 128];                                    \
      short8 hf2 = *(const short8*)&us[hb + 256];                                    \
      short8 hf3 = *(const short8*)&us[hb + 384];                                    \
      ACC2[0] = __builtin_amdgcn_mfma_f32_16x16x32_bf16(wrg[kk], hf0, ACC2[0], 0, 0, 0);\
      ACC2[1] = __builtin_amdgcn_mfma_f32_16x16x32_bf16(wrg[kk], hf1, ACC2[1], 0, 0, 0);\
      ACC2[2] = __builtin_amdgcn_mfma_f32_16x16x32_bf16(wrg[kk], hf2, ACC2[2], 0, 0, 0);\
      ACC2[3] = __builtin_amdgcn_mfma_f32_16x16x32_bf16(wrg[kk], hf3, ACC2[3], 0, 0, 0);\
    }                                                                                \
  }

#define EPI_HALF(M0, ACC2)                                                           \
  {                                                                                  \
    _Pragma("unroll")                                                                \
    for (int i = 0; i < 4; ++i) {                                                    \
      int d = (M0) + lq * 4 + i;                                                     \
      float bb = b2_s[d] + fcq_s[d];                                                 \
      size_t rowoff = ((size_t)b * D + d) * L + l0;                                  \
      _Pragma("unroll")                                                              \
      for (int nt = 0; nt < 4; ++nt) {                                               \
        int tok = nt * 16 + lr;                                                      \
        dst[rowoff + tok] = ACC2[nt][i] + bb + src[rowoff + tok];                    \
      }                                                                              \
    }                                                                                \
  }

__global__ __launch_bounds__(512, 4) void k_ffn(
    const float* src, float* dst, const float* __restrict__ fcq,
    const unsigned short* __restrict__ w1b, const float* __restrict__ b1,
    const unsigned short* __restrict__ w2b, const float* __restrict__ b2,
    const float* __restrict__ g, const float* __restrict__ be) {
  __shared__ __align__(16) unsigned short us[32768];   // 64 KB
  __shared__ float fcq_s[D], g_s[D], be_s[D], b2_s[D];
  __shared__ float part1[8][MT], part2[8][MT];
  __shared__ float mu_s[MT], rs_s[MT];

  int blk = blockIdx.x;
  int b = blk >> 5;
  int l0 = (blk & 31) * MT;
  int tid = threadIdx.x;
  int t = tid & 63, dg = tid >> 6;
  int wv = tid >> 6, lane = tid & 63, lr = lane & 15, lq = lane >> 4;

  if (tid < D) {
    fcq_s[tid] = fcq[b * D + tid];
    g_s[tid] = g[tid]; be_s[tid] = be[tid]; b2_s[tid] = b2[tid];
  }
  __syncthreads();

  // ---- stage 1: load tile, add fcq, token LN stats ----
  const float* vcol = src + ((size_t)b * D + dg * 32) * L + l0 + t;
  float vv[32];
  float s1 = 0.f, s2 = 0.f;
  #pragma unroll
  for (int j = 0; j < 32; ++j) {
    float x = vcol[(size_t)j * L] + fcq_s[dg * 32 + j];
    vv[j] = x; s1 += x; s2 += x * x;
  }
  part1[dg][t] = s1; part2[dg][t] = s2;
  __syncthreads();
  if (tid < MT) {
    float a = 0.f, c = 0.f;
    #pragma unroll
    for (int q = 0; q < 8; ++q) { a += part1[q][tid]; c += part2[q][tid]; }
    float mu = a * (1.f / D);
    float var = c * (1.f / D) - mu * mu;
    mu_s[tid] = mu; rs_s[tid] = rsqrtf(var + EPS_LN);
  }
  __syncthreads();
  {
    float mu = mu_s[t], rs = rs_s[t];
    #pragma unroll
    for (int lq2 = 0; lq2 < 4; ++lq2) {
      uint4 pw;
      unsigned* pp = &pw.x;
      #pragma unroll
      for (int jj = 0; jj < 4; ++jj) {
        int d0 = dg * 32 + lq2 * 8 + jj * 2;
        pp[jj] = pk2bf((vv[lq2 * 8 + jj * 2]     - mu) * rs * g_s[d0]     + be_s[d0],
                       (vv[lq2 * 8 + jj * 2 + 1] - mu) * rs * g_s[d0 + 1] + be_s[d0 + 1]);
      }
      *(uint4*)&us[((dg * 4 + lq2) * 64 + t) * 8] = pw;
    }
  }
  __syncthreads();

  float4_ zero = {0.f, 0.f, 0.f, 0.f};

  // ---- GEMM1 phase A: h in [wv*32, +32) -> h1 upper ----
  {
    float4_ accA[2][4];
    #pragma unroll
    for (int i = 0; i < 2; ++i)
      #pragma unroll
      for (int j = 0; j < 4; ++j) accA[i][j] = zero;
    GEMM1_HALF(wv * 32, accA)
    H1_WRITE(wv * 32, accA)
  }
  // ---- GEMM1 phase B: h in [256+wv*32, +32) -> h1 lower (alias a_tile) ----
  {
    float4_ accB[2][4];
    #pragma unroll
    for (int i = 0; i < 2; ++i)
      #pragma unroll
      for (int j = 0; j < 4; ++j) accB[i][j] = zero;
    GEMM1_HALF(256 + wv * 32, accB)
    __syncthreads();               // all a_tile reads done (WAR)
    H1_WRITE(256 + wv * 32, accB)
  }
  __syncthreads();                 // h1 fully visible

  // ---- GEMM2 phases ----
  {
    float4_ acc2[4];
    #pragma unroll
    for (int j = 0; j < 4; ++j) acc2[j] = zero;
    GEMM2_HALF(wv * 16, acc2)
    EPI_HALF(wv * 16, acc2)
  }
  {
    float4_ acc2[4];
    #pragma unroll
    for (int j = 0; j < 4; ++j) acc2[j] = zero;
    GEMM2_HALF(128 + wv * 16, acc2)
    EPI_HALF(128 + wv * 16, acc2)
  }
}

// ---- final: y = relu(skip0+skip1); batchnorm over B per channel d ----
__global__ void k_bn(const float* __restrict__ s0, const float* __restrict__ s1,
                     float* __restrict__ out) {
  int d = threadIdx.x;
  float s = 0.f, q = 0.f;
  for (int b = 0; b < B; ++b) {
    float y = fmaxf(s0[b * D + d] + s1[b * D + d], 0.f);
    s += y; q += y * y;
  }
  float mu = s * (1.f / B);
  float var = q * (1.f / B) - mu * mu;
  float rs = rsqrtf(var + EPS_BN);
  for (int b = 0; b < B; ++b) {
    float y = fmaxf(s0[b * D + d] + s1[b * D + d], 0.f);
    out[b * D + d] = (y - mu) * rs;
  }
}

extern "C" void kernel_launch(void* const* d_in, const int* in_sizes, int n_in,
                              void* d_out, int out_size, void* d_ws, size_t ws_size,
                              hipStream_t stream) {
  const float* x    = (const float*)d_in[0];
  const float* wk   = (const float*)d_in[1];
  const float* wq   = (const float*)d_in[2];
  const float* fcqw = (const float*)d_in[3];
  const float* fcw  = (const float*)d_in[4];
  const float* fcb  = (const float*)d_in[5];
  const float* ag   = (const float*)d_in[6];
  const float* abt  = (const float*)d_in[7];
  const float* w1   = (const float*)d_in[8];
  const float* b1   = (const float*)d_in[9];
  const float* w2   = (const float*)d_in[10];
  const float* b2   = (const float*)d_in[11];
  const float* fg   = (const float*)d_in[12];
  const float* fb   = (const float*)d_in[13];
  float* out = (float*)d_out;

  char* p = (char*)d_ws;
  float* v_ws = (float*)p;  p += (size_t)B * D * L * 4;
  float* m    = (float*)p;  p += (size_t)B * L * 4;
  float* r    = (float*)p;  p += (size_t)B * L * 4;
  float* sc   = (float*)p;  p += (size_t)B * L * 4;
  float* S1p  = (float*)p;  p += (size_t)B * 32 * D * 4;
  float* S2p  = (float*)p;  p += (size_t)B * 32 * D * 4;
  float* gw   = (float*)p;  p += (size_t)B * D * 4;
  float* A1   = (float*)p;  p += (size_t)B * D * 4;
  float* A2   = (float*)p;  p += (size_t)B * D * 4;
  float* fcqv = (float*)p;  p += (size_t)B * D * 4;
  float* sk0  = (float*)p;  p += (size_t)B * D * 4;
  float* sk1  = (float*)p;  p += (size_t)B * D * 4;
  unsigned short* w1b = (unsigned short*)p; p += (size_t)2 * H * D * 2;
  unsigned short* w2b = (unsigned short*)p; p += (size_t)2 * D * H * 2;

  k_convw<<<512, 256, 0, stream>>>(w1, w2, w1b, w2b);

  for (int i = 0; i < 2; ++i) {
    const float* src = (i == 0) ? x : v_ws;
    float* dst = v_ws;
    k_pass1<<<B * 32, 512, 0, stream>>>(src, m, r, S1p, S2p);
    k_qproj<<<B, 256, 0, stream>>>(S1p, S2p, ag + i * D, abt + i * D,
                                   wq + (size_t)i * KP * 2 * D,
                                   wk + (size_t)i * KP * D, gw);
    k_scores<<<B * L / 256, 256, 0, stream>>>(src, m, r, gw, sc);
    k_redw<<<B * 8, 256, 0, stream>>>(src, m, r, sc, A1, A2);
    k_skip<<<B, 256, 0, stream>>>(A1, A2, ag + i * D, abt + i * D,
                                  fcw + (size_t)i * D * 2 * D, fcb + i * D,
                                  fcqw + (size_t)i * D * D,
                                  (i == 0) ? sk0 : sk1, fcqv);
    k_ffn<<<B * (L / MT), 512, 0, stream>>>(src, dst, fcqv,
                                            w1b + (size_t)i * H * D, b1 + i * H,
                                            w2b + (size_t)i * D * H, b2 + i * D,
                                            fg + i * D, fb + i * D);
  }
  k_bn<<<1, 256, 0, stream>>>(sk0, sk1, out);
}